// Round 1
// baseline (1171.867 us; speedup 1.0000x reference)
//
#include <hip/hip_runtime.h>

#define NS 2
#define NH 8
#define NL 4
#define NP 4
#define E  256
#define HD 32
#define Q  16

__launch_bounds__(256, 2)
__global__ void tsa_fused(const float* __restrict__ query,
                          const float* __restrict__ key_hist,
                          const float* __restrict__ value_hist,
                          const float* __restrict__ refpts,
                          const float* __restrict__ Wq, const float* __restrict__ bq,
                          const float* __restrict__ Wk, const float* __restrict__ bk,
                          const float* __restrict__ Wv, const float* __restrict__ bv,
                          const float* __restrict__ Woff, const float* __restrict__ boff,
                          const float* __restrict__ Wout, const float* __restrict__ bout,
                          float* __restrict__ out)
{
    const int b = blockIdx.x;
    const int t = threadIdx.x;

    // LDS: ~79 KB total -> 2 blocks/CU max
    __shared__ float xq[Q][E];          // query rows (also residual)
    __shared__ float xk[Q][E];          // key_hist rows
    __shared__ float xv[Q][E];          // value_hist rows
    __shared__ float accsum[Q][E];      // mean-over-seq sampled output (q, e=h*32+d)
    __shared__ float qh_s[Q][33];       // per-head q projection (padded)
    __shared__ float kh_s[NS][Q][33];   // per-head k projection, both seqs
    __shared__ float vh_s[NS][Q][33];   // per-head v projection, both seqs
    __shared__ float off_s[Q][32];      // per-head offsets (l,p,c)
    __shared__ float attn_s[NS][Q][Q];  // scores -> softmax weights
    __shared__ float rp_s[Q][NL][2];    // reference points

    // ---- load per-batch inputs ----
    const float* qb = query      + (size_t)b * Q * E;
    const float* kb = key_hist   + (size_t)b * Q * E;
    const float* vb = value_hist + (size_t)b * Q * E;
    for (int i = t; i < Q * E / 4; i += 256) {
        ((float4*)xq)[i] = ((const float4*)qb)[i];
        ((float4*)xk)[i] = ((const float4*)kb)[i];
        ((float4*)xv)[i] = ((const float4*)vb)[i];
    }
    if (t < Q * NL * 2) ((float*)rp_s)[t] = refpts[(size_t)b * Q * NL * 2 + t];
    __syncthreads();

    const int j  = t & 31;   // column within head / channel d
    const int qi = t >> 5;   // 0..7 -> rows qi and qi+8

    for (int h = 0; h < NH; ++h) {
        const int col = h * 32 + j;
        // ---- per-head projections: 6 GEMM slices [16x256]@[256x32] ----
        {
            const int r0 = qi, r1 = qi + 8;
            float aq0 = 0.f, aq1 = 0.f;
            float ak00 = 0.f, ak01 = 0.f, ak10 = 0.f, ak11 = 0.f;
            float av00 = 0.f, av01 = 0.f, av10 = 0.f, av11 = 0.f;
            float ao0 = 0.f, ao1 = 0.f;
            #pragma unroll 4
            for (int k = 0; k < E; ++k) {
                const float wq = Wq[k * E + col];
                const float wk = Wk[k * E + col];
                const float wv = Wv[k * E + col];
                const float wo = Woff[k * E + col];
                const float x0 = xq[r0][k], x1 = xq[r1][k];
                const float y0 = xk[r0][k], y1 = xk[r1][k];
                const float z0 = xv[r0][k], z1 = xv[r1][k];
                aq0  += x0 * wq;  aq1  += x1 * wq;
                ak00 += x0 * wk;  ak01 += x1 * wk;
                ak10 += y0 * wk;  ak11 += y1 * wk;
                av00 += x0 * wv;  av01 += x1 * wv;
                av10 += z0 * wv;  av11 += z1 * wv;
                ao0  += x0 * wo;  ao1  += x1 * wo;
            }
            const float bqv = bq[col], bkv = bk[col], bvv = bv[col], bov = boff[col];
            qh_s[r0][j]    = aq0  + bqv;  qh_s[r1][j]    = aq1  + bqv;
            kh_s[0][r0][j] = ak00 + bkv;  kh_s[0][r1][j] = ak01 + bkv;
            kh_s[1][r0][j] = ak10 + bkv;  kh_s[1][r1][j] = ak11 + bkv;
            vh_s[0][r0][j] = av00 + bvv;  vh_s[0][r1][j] = av01 + bvv;
            vh_s[1][r0][j] = av10 + bvv;  vh_s[1][r1][j] = av11 + bvv;
            off_s[r0][j]   = ao0  + bov;  off_s[r1][j]   = ao1  + bov;
        }
        __syncthreads();

        // ---- attention scores: (q,k) per thread, both seqs ----
        {
            const int sq = t >> 4;   // 0..15
            const int sk = t & 15;
            #pragma unroll
            for (int s = 0; s < NS; ++s) {
                float acc = 0.f;
                #pragma unroll
                for (int d = 0; d < HD; ++d)
                    acc += qh_s[sq][d] * kh_s[s][sk][d];
                attn_s[s][sq][sk] = acc;
            }
        }
        __syncthreads();

        // ---- softmax over the 16 keys (32 rows total) ----
        if (t < NS * Q) {
            const int s = t >> 4, q = t & 15;
            float m = attn_s[s][q][0];
            #pragma unroll
            for (int k2 = 1; k2 < Q; ++k2) m = fmaxf(m, attn_s[s][q][k2]);
            float tmp[Q];
            float sum = 0.f;
            #pragma unroll
            for (int k2 = 0; k2 < Q; ++k2) {
                const float e_ = __expf(attn_s[s][q][k2] - m);
                tmp[k2] = e_;
                sum += e_;
            }
            const float inv = 1.0f / sum;
            #pragma unroll
            for (int k2 = 0; k2 < Q; ++k2) attn_s[s][q][k2] = tmp[k2] * inv;
        }
        __syncthreads();

        // ---- bilinear sampling on 2x2 levels + attention-weighted reduce ----
        {
            const int d = j;
            #pragma unroll
            for (int rr = 0; rr < 2; ++rr) {
                const int q = qi + rr * 8;
                float acc0 = 0.f, acc1 = 0.f;
                #pragma unroll
                for (int s = 0; s < NS; ++s) {
                    float a = 0.f;
                    #pragma unroll
                    for (int l = 0; l < NL; ++l) {
                        const float rpx = rp_s[q][l][0], rpy = rp_s[q][l][1];
                        #pragma unroll
                        for (int p = 0; p < NP; ++p) {
                            const int kk = l * NP + p;
                            const float ox = off_s[q][kk * 2], oy = off_s[q][kk * 2 + 1];
                            // grid = 2*(rp + off/2) - 1; pixel coord = (grid+1)*1 - 0.5
                            const float gx = 2.0f * (rpx + ox * 0.5f) - 0.5f;
                            const float gy = 2.0f * (rpy + oy * 0.5f) - 0.5f;
                            const float x0f = floorf(gx), y0f = floorf(gy);
                            const int ix0 = (int)x0f, iy0 = (int)y0f;
                            const float wx1 = gx - x0f, wx0 = 1.0f - wx1;
                            const float wy1 = gy - y0f, wy0 = 1.0f - wy1;
                            float v00 = 0.f, v01 = 0.f, v10 = 0.f, v11 = 0.f;
                            const int base = l * 4;
                            if (iy0 >= 0 && iy0 < 2) {
                                if (ix0     >= 0 && ix0     < 2) v00 = vh_s[s][base + iy0 * 2 + ix0    ][d];
                                if (ix0 + 1 >= 0 && ix0 + 1 < 2) v01 = vh_s[s][base + iy0 * 2 + ix0 + 1][d];
                            }
                            if (iy0 + 1 >= 0 && iy0 + 1 < 2) {
                                if (ix0     >= 0 && ix0     < 2) v10 = vh_s[s][base + (iy0 + 1) * 2 + ix0    ][d];
                                if (ix0 + 1 >= 0 && ix0 + 1 < 2) v11 = vh_s[s][base + (iy0 + 1) * 2 + ix0 + 1][d];
                            }
                            const float sval = v00 * (wx0 * wy0) + v01 * (wx1 * wy0)
                                             + v10 * (wx0 * wy1) + v11 * (wx1 * wy1);
                            a += attn_s[s][q][kk] * sval;
                        }
                    }
                    if (s == 0) acc0 = a; else acc1 = a;
                }
                accsum[q][h * 32 + d] = 0.5f * (acc0 + acc1);
            }
        }
        __syncthreads();
    }

    // ---- final output GEMM: out[b] = accsum @ Wout + bout + residual ----
    {
        float acc[Q];
        #pragma unroll
        for (int q = 0; q < Q; ++q) acc[q] = 0.f;
        #pragma unroll 4
        for (int k = 0; k < E; ++k) {
            const float w = Wout[k * E + t];
            #pragma unroll
            for (int q = 0; q < Q; ++q) acc[q] += accsum[q][k] * w;
        }
        const float bo = bout[t];
        float* ob = out + (size_t)b * Q * E;
        #pragma unroll
        for (int q = 0; q < Q; ++q)
            ob[q * E + t] = acc[q] + bo + xq[q][t];
    }
}

extern "C" void kernel_launch(void* const* d_in, const int* in_sizes, int n_in,
                              void* d_out, int out_size, void* d_ws, size_t ws_size,
                              hipStream_t stream) {
    const float* query      = (const float*)d_in[0];
    const float* key_hist   = (const float*)d_in[1];
    const float* value_hist = (const float*)d_in[2];
    const float* refpts     = (const float*)d_in[3];
    // d_in[4] = spatial_shapes (all 2x2, static in reference) -- unused
    const float* Wq   = (const float*)d_in[5];
    const float* bq   = (const float*)d_in[6];
    const float* Wk   = (const float*)d_in[7];
    const float* bk   = (const float*)d_in[8];
    const float* Wv   = (const float*)d_in[9];
    const float* bv   = (const float*)d_in[10];
    const float* Woff = (const float*)d_in[11];
    const float* boff = (const float*)d_in[12];
    const float* Wout = (const float*)d_in[13];
    const float* bout = (const float*)d_in[14];
    float* outp = (float*)d_out;

    const int bs = in_sizes[0] / (Q * E);
    tsa_fused<<<bs, 256, 0, stream>>>(query, key_hist, value_hist, refpts,
                                      Wq, bq, Wk, bk, Wv, bv, Woff, boff,
                                      Wout, bout, outp);
}

// Round 2
// 660.013 us; speedup vs baseline: 1.7755x; 1.7755x over previous
//
#include <hip/hip_runtime.h>

#define Q  16
#define E  256
#define GH 4   // heads per group (2 groups of 4)

typedef float  f32x4  __attribute__((ext_vector_type(4)));
typedef __bf16 bf16x8 __attribute__((ext_vector_type(8)));

__device__ __forceinline__ unsigned short f2bf(float f) {
    union { float f; unsigned u; } v; v.f = f;
    unsigned r = v.u + 0x7FFFu + ((v.u >> 16) & 1u);
    return (unsigned short)(r >> 16);
}
__device__ __forceinline__ float bf2f(unsigned short s) {
    union { unsigned u; float f; } v; v.u = ((unsigned)s) << 16;
    return v.f;
}

// ---- weight transpose+convert: WT[m][col][k] bf16, m in {q,k,v,off,out} ----
__global__ void wtrans(const float* __restrict__ Wq, const float* __restrict__ Wk,
                       const float* __restrict__ Wv, const float* __restrict__ Woff,
                       const float* __restrict__ Wout, unsigned short* __restrict__ WT) {
    int id = blockIdx.x * 256 + threadIdx.x;     // 5*65536 total
    int m = id >> 16, e = id & 65535;
    int col = e >> 8, k = e & 255;
    const float* W = (m == 0) ? Wq : (m == 1) ? Wk : (m == 2) ? Wv : (m == 3) ? Woff : Wout;
    WT[id] = f2bf(W[k * 256 + col]);
}

__launch_bounds__(256, 2)
__global__ void tsa_mfma(const float* __restrict__ query, const float* __restrict__ key_hist,
                         const float* __restrict__ value_hist, const float* __restrict__ refpts,
                         const unsigned short* __restrict__ WT,
                         const float* __restrict__ bq, const float* __restrict__ bk,
                         const float* __restrict__ bv, const float* __restrict__ boff,
                         const float* __restrict__ bout, float* __restrict__ out)
{
    const int b = blockIdx.x;
    const int t = threadIdx.x;
    const int lane = t & 63;
    const int w = t >> 6;         // wave 0..3
    const int l15 = lane & 15;
    const int lhi = lane >> 4;    // 0..3
    const int q4 = lhi * 4;

    __shared__ __attribute__((aligned(16))) unsigned short xs[3][Q * E];   // swizzled bf16, 24KB
    __shared__ __attribute__((aligned(16))) unsigned short accbf[Q * E];   // swizzled bf16, 8KB
    __shared__ float rp_s[128];
    __shared__ __attribute__((aligned(16))) unsigned short qh_s[GH * Q * 32];      // [h][q][d]
    __shared__ __attribute__((aligned(16))) unsigned short kh_s[2 * GH * Q * 32];  // [s][h][k2][d]
    __shared__ __attribute__((aligned(16))) unsigned short vhT[GH * 32 * 32];      // [h][d][s*16+pos]
    __shared__ __attribute__((aligned(16))) unsigned short off_s[GH * Q * 32];     // [h][q][c]
    __shared__ float attn_s[2 * GH * Q * 17];                                      // padded rows
    __shared__ __attribute__((aligned(16))) unsigned short Wp[GH * Q * 32];        // [h][q][s*16+pos]

    // ---- stage x (f32 -> bf16, XOR-swizzled rows) ----
    {
        const float* s0 = query      + (size_t)b * 4096;
        const float* s1 = key_hist   + (size_t)b * 4096;
        const float* s2 = value_hist + (size_t)b * 4096;
        #pragma unroll
        for (int it = 0; it < 4; ++it) {
            int i = t + it * 256;                 // chunk of 4 floats
            int row = i >> 6, kc = i & 63;
            int byte = row * 512 + ((kc * 8) ^ ((row & 7) << 4));
            float4 v0 = ((const float4*)s0)[i];
            float4 v1 = ((const float4*)s1)[i];
            float4 v2 = ((const float4*)s2)[i];
            ushort4 o;
            o.x = f2bf(v0.x); o.y = f2bf(v0.y); o.z = f2bf(v0.z); o.w = f2bf(v0.w);
            *(ushort4*)((char*)xs[0] + byte) = o;
            o.x = f2bf(v1.x); o.y = f2bf(v1.y); o.z = f2bf(v1.z); o.w = f2bf(v1.w);
            *(ushort4*)((char*)xs[1] + byte) = o;
            o.x = f2bf(v2.x); o.y = f2bf(v2.y); o.z = f2bf(v2.z); o.w = f2bf(v2.w);
            *(ushort4*)((char*)xs[2] + byte) = o;
        }
        if (t < 128) rp_s[t] = refpts[(size_t)b * 128 + t];
    }
    __syncthreads();

    for (int g = 0; g < 2; ++g) {
        // ---- projections: 48 tiles (6 proj x 8 col-tiles), 12 per wave ----
        f32x4 acc[12];
        #pragma unroll
        for (int i = 0; i < 12; ++i) acc[i] = (f32x4){0.f, 0.f, 0.f, 0.f};

        for (int kt = 0; kt < 8; ++kt) {
            bf16x8 af[3];
            {
                int abyte = l15 * 512 + ((lhi * 16 + kt * 64) ^ ((l15 & 7) << 4));
                af[0] = *(const bf16x8*)((const char*)xs[0] + abyte);
                af[1] = *(const bf16x8*)((const char*)xs[1] + abyte);
                af[2] = *(const bf16x8*)((const char*)xs[2] + abyte);
            }
            bf16x8 bfr[12];
            #pragma unroll
            for (int i = 0; i < 12; ++i) {
                int tid = w + 4 * i;
                int p = tid >> 3, n = tid & 7;
                int widx = (p + 1) >> 1;          // {q,k,k,v,v,off} -> {0,1,1,2,2,3}
                int col = g * 128 + n * 16 + l15;
                bfr[i] = *(const bf16x8*)(WT + (size_t)widx * 65536 + col * 256 + kt * 32 + lhi * 8);
            }
            #pragma unroll
            for (int i = 0; i < 12; ++i) {
                int tid = w + 4 * i;
                int p = tid >> 3;
                int im = (p == 2) ? 1 : ((p == 4) ? 2 : 0);
                acc[i] = __builtin_amdgcn_mfma_f32_16x16x32_bf16(af[im], bfr[i], acc[i], 0, 0, 0);
            }
        }
        // epilogue: bias + bf16 + scatter to per-consumer layouts
        #pragma unroll
        for (int i = 0; i < 12; ++i) {
            int tid = w + 4 * i;
            int p = tid >> 3, n = tid & 7;
            int h = n >> 1, dh = n & 1;
            int colw = g * 128 + n * 16 + l15;
            const float* bp_ = (p == 0) ? bq : (p <= 2) ? bk : (p <= 4) ? bv : boff;
            float bval = bp_[colw];
            int dcol = dh * 16 + l15;
            #pragma unroll
            for (int r = 0; r < 4; ++r) {
                unsigned short u = f2bf(acc[i][r] + bval);
                int row = q4 + r;  // q / k2 / pos
                if (p == 0)      qh_s[(h * Q + row) * 32 + dcol] = u;
                else if (p <= 2) kh_s[(((p - 1) * GH + h) * Q + row) * 32 + dcol] = u;
                else if (p <= 4) vhT[(h * 32 + dcol) * 32 + (p - 3) * 16 + row] = u;
                else             off_s[(h * Q + row) * 32 + dcol] = u;
            }
        }
        __syncthreads();

        // ---- attention scores: MFMA qh @ kh^T (K=32), 2 per wave ----
        #pragma unroll
        for (int j2 = 0; j2 < 2; ++j2) {
            int id = w * 2 + j2;
            int s = id >> 2, h = id & 3;
            bf16x8 a  = *(const bf16x8*)((const char*)qh_s + h * 1024 + l15 * 64 + lhi * 16);
            bf16x8 bb = *(const bf16x8*)((const char*)kh_s + (s * 4 + h) * 1024 + l15 * 64 + lhi * 16);
            f32x4 c = (f32x4){0.f, 0.f, 0.f, 0.f};
            c = __builtin_amdgcn_mfma_f32_16x16x32_bf16(a, bb, c, 0, 0, 0);
            #pragma unroll
            for (int r = 0; r < 4; ++r)
                attn_s[((s * GH + h) * Q + q4 + r) * 17 + l15] = c[r];
        }
        __syncthreads();

        // ---- softmax over 16 keys, 128 rows ----
        if (t < 128) {
            float* row = &attn_s[t * 17];
            float m = row[0];
            #pragma unroll
            for (int k2 = 1; k2 < 16; ++k2) m = fmaxf(m, row[k2]);
            float e[16]; float sum = 0.f;
            #pragma unroll
            for (int k2 = 0; k2 < 16; ++k2) { e[k2] = __expf(row[k2] - m); sum += e[k2]; }
            float inv = 1.f / sum;
            #pragma unroll
            for (int k2 = 0; k2 < 16; ++k2) row[k2] = e[k2] * inv;
        }
        __syncthreads();

        // ---- bilinear coords -> per-position weights W[s,pos] (scatter via selects) ----
        {
            int h = t >> 6, qq = (t >> 2) & 15, lv = t & 3;
            float rpx = rp_s[(qq * 4 + lv) * 2 + 0];
            float rpy = rp_s[(qq * 4 + lv) * 2 + 1];
            float b0[4] = {0, 0, 0, 0}, b1[4] = {0, 0, 0, 0};
            #pragma unroll
            for (int p = 0; p < 4; ++p) {
                int kk = lv * 4 + p;
                float ox = bf2f(off_s[(h * Q + qq) * 32 + 2 * kk]);
                float oy = bf2f(off_s[(h * Q + qq) * 32 + 2 * kk + 1]);
                float gx = 2.f * rpx + ox - 0.5f;     // norm=(2,2): off/2 then *2
                float gy = 2.f * rpy + oy - 0.5f;
                float x0f = floorf(gx), y0f = floorf(gy);
                int ix0 = (int)x0f, iy0 = (int)y0f;
                float wx1 = gx - x0f, wx0 = 1.f - wx1;
                float wy1 = gy - y0f, wy0 = 1.f - wy1;
                float a0 = attn_s[((0 * GH + h) * Q + qq) * 17 + kk];
                float a1 = attn_s[((1 * GH + h) * Q + qq) * 17 + kk];
                #pragma unroll
                for (int c4 = 0; c4 < 4; ++c4) {
                    int dy = c4 >> 1, dx = c4 & 1;
                    int iy = iy0 + dy, ix = ix0 + dx;
                    float cw = (dx ? wx1 : wx0) * (dy ? wy1 : wy0);
                    bool valid = (ix >= 0) & (ix < 2) & (iy >= 0) & (iy < 2);
                    cw = valid ? cw : 0.f;
                    int pix = iy * 2 + ix;
                    #pragma unroll
                    for (int sl = 0; sl < 4; ++sl) {
                        float add = (pix == sl) ? cw : 0.f;
                        b0[sl] += add * a0;
                        b1[sl] += add * a1;
                    }
                }
            }
            ushort4 o0, o1;
            o0.x = f2bf(b0[0]); o0.y = f2bf(b0[1]); o0.z = f2bf(b0[2]); o0.w = f2bf(b0[3]);
            o1.x = f2bf(b1[0]); o1.y = f2bf(b1[1]); o1.z = f2bf(b1[2]); o1.w = f2bf(b1[3]);
            *(ushort4*)((char*)Wp + (h * Q + qq) * 64 + lv * 8) = o0;
            *(ushort4*)((char*)Wp + (h * Q + qq) * 64 + 32 + lv * 8) = o1;
        }
        __syncthreads();

        // ---- PV: out[q][d] = sum_{s,pos} W * vh, K=32, per wave one head ----
        {
            int h = w;
            bf16x8 a = *(const bf16x8*)((const char*)Wp + (h * Q + l15) * 64 + lhi * 16);
            #pragma unroll
            for (int dh = 0; dh < 2; ++dh) {
                bf16x8 bb = *(const bf16x8*)((const char*)vhT + (h * 32 + dh * 16 + l15) * 64 + lhi * 16);
                f32x4 c = (f32x4){0.f, 0.f, 0.f, 0.f};
                c = __builtin_amdgcn_mfma_f32_16x16x32_bf16(a, bb, c, 0, 0, 0);
                int col = (g * GH + h) * 32 + dh * 16 + l15;
                #pragma unroll
                for (int r = 0; r < 4; ++r) {
                    int row = q4 + r;
                    int byte = row * 512 + ((col * 2) ^ ((row & 7) << 4));
                    *(unsigned short*)((char*)accbf + byte) = f2bf(0.5f * c[r]);
                }
            }
        }
        __syncthreads();
    }

    // ---- final: out = accbf @ Wout + bout + residual ----
    {
        f32x4 facc[4];
        #pragma unroll
        for (int i = 0; i < 4; ++i) facc[i] = (f32x4){0.f, 0.f, 0.f, 0.f};
        for (int kt = 0; kt < 8; ++kt) {
            int abyte = l15 * 512 + ((lhi * 16 + kt * 64) ^ ((l15 & 7) << 4));
            bf16x8 a = *(const bf16x8*)((const char*)accbf + abyte);
            #pragma unroll
            for (int i = 0; i < 4; ++i) {
                int col = (w * 4 + i) * 16 + l15;
                facc[i] = __builtin_amdgcn_mfma_f32_16x16x32_bf16(
                    a, *(const bf16x8*)(WT + (size_t)4 * 65536 + col * 256 + kt * 32 + lhi * 8),
                    facc[i], 0, 0, 0);
            }
        }
        #pragma unroll
        for (int i = 0; i < 4; ++i) {
            int col = (w * 4 + i) * 16 + l15;
            float bo = bout[col];
            #pragma unroll
            for (int r = 0; r < 4; ++r) {
                int row = q4 + r;
                size_t idx = (size_t)b * 4096 + row * 256 + col;
                out[idx] = facc[i][r] + bo + query[idx];
            }
        }
    }
}

extern "C" void kernel_launch(void* const* d_in, const int* in_sizes, int n_in,
                              void* d_out, int out_size, void* d_ws, size_t ws_size,
                              hipStream_t stream) {
    const float* query      = (const float*)d_in[0];
    const float* key_hist   = (const float*)d_in[1];
    const float* value_hist = (const float*)d_in[2];
    const float* refpts     = (const float*)d_in[3];
    const float* Wq   = (const float*)d_in[5];
    const float* bq   = (const float*)d_in[6];
    const float* Wk   = (const float*)d_in[7];
    const float* bk   = (const float*)d_in[8];
    const float* Wv   = (const float*)d_in[9];
    const float* bv   = (const float*)d_in[10];
    const float* Woff = (const float*)d_in[11];
    const float* boff = (const float*)d_in[12];
    const float* Wout = (const float*)d_in[13];
    const float* bout = (const float*)d_in[14];
    float* outp = (float*)d_out;

    unsigned short* WT = (unsigned short*)d_ws;   // 5*65536 bf16 = 640KB
    const int bs = in_sizes[0] / (Q * E);

    wtrans<<<5 * 65536 / 256, 256, 0, stream>>>(Wq, Wk, Wv, Woff, Wout, WT);
    tsa_mfma<<<bs, 256, 0, stream>>>(query, key_hist, value_hist, refpts, WT,
                                     bq, bk, bv, boff, bout, outp);
}

// Round 3
// 154.729 us; speedup vs baseline: 7.5737x; 4.2656x over previous
//
#include <hip/hip_runtime.h>

#define Q  16
#define E  256

typedef float  f32x4  __attribute__((ext_vector_type(4)));
typedef __bf16 bf16x8 __attribute__((ext_vector_type(8)));

__device__ __forceinline__ unsigned short f2bf(float f) {
    union { float f; unsigned u; } v; v.f = f;
    unsigned r = v.u + 0x7FFFu + ((v.u >> 16) & 1u);
    return (unsigned short)(r >> 16);
}
__device__ __forceinline__ ushort4 pack4(float a, float b, float c, float d) {
    ushort4 o; o.x = f2bf(a); o.y = f2bf(b); o.z = f2bf(c); o.w = f2bf(d); return o;
}

// ws layout (bytes):
//   0       .. 524288 : WTproj_sw  [8 colblk][2 khalf][128 c][256B], XOR-swizzled
//   524288  .. 655360 : WToutT     [256 col][256 k] bf16, plain
//   655360  .. 659456 : biasall    [1024] f32  (bq|bk|bv|boff)
//   1MB     ..        : per-chunk: PQ[CB*4096]s, PK[CB*8192]s, PVt[CB*8192]s, PO[CB*4096]s
#define CHB (1u << 20)

// ---------------- K1: weight prep ----------------
__global__ void wprep(const float* __restrict__ Wq, const float* __restrict__ Wk,
                      const float* __restrict__ Wv, const float* __restrict__ Woff,
                      const float* __restrict__ Wout,
                      const float* __restrict__ bq, const float* __restrict__ bk,
                      const float* __restrict__ bv, const float* __restrict__ boff,
                      unsigned char* __restrict__ ws) {
    int id = blockIdx.x * 256 + threadIdx.x;      // 1284*256 = 328704 = 1280*256 + 1024
    if (id < 1280 * 256) {
        int gc = id >> 8, k = id & 255;
        if (gc < 1024) {
            const float* W = (gc < 256) ? Wq : (gc < 512) ? Wk : (gc < 768) ? Wv : Woff;
            int cb = gc >> 7, c = gc & 127;
            int kh = k >> 7, khl = k & 127;
            unsigned off = cb * 65536 + kh * 32768 + c * 256 + (((unsigned)(khl * 2)) ^ ((c & 7) << 4));
            *(unsigned short*)(ws + off) = f2bf(W[k * 256 + (gc & 255)]);
        } else {
            int col = gc - 1024;                  // 0..255
            ((unsigned short*)(ws + 524288))[col * 256 + k] = f2bf(Wout[k * 256 + col]);
        }
    } else {
        int i = id - 1280 * 256;                  // 0..1023
        const float* B = (i < 256) ? bq : (i < 512) ? bk : (i < 768) ? bv : boff;
        ((float*)(ws + 655360))[i] = B[i & 255];
    }
}

// ---------------- K2: projection GEMM ----------------
// grid = MT*12; MT = CB/8 (128 rows per M-tile). pid = bid/MT:
//  0,1: query->PQ   2,3: query->PK[s0]  4,5: query->PVt[s0]  6,7: query->PO
//  8,9: key_hist->PK[s1]   10,11: value_hist->PVt[s1]
__launch_bounds__(512, 4)
__global__ void proj_gemm(const float* __restrict__ query, const float* __restrict__ keyh,
                          const float* __restrict__ valh, unsigned char* __restrict__ ws,
                          int b0, int MT, int CB) {
    __shared__ __attribute__((aligned(16))) unsigned char As[32768];
    __shared__ __attribute__((aligned(16))) unsigned char Bs[32768];
    const int bid = blockIdx.x;
    const int mt = bid % MT, pid = bid / MT;
    const int part = (pid < 8) ? 0 : (pid < 10) ? 1 : 2;
    const int cb_w = (pid < 8) ? (pid) : (pid < 10) ? (pid - 8 + 2) : (pid - 10 + 4);
    const float* xsrc = (part == 0) ? query : (part == 1) ? keyh : valh;
    const unsigned char* wB = ws + (size_t)cb_w * 65536;
    const float* biasall = (const float*)(ws + 655360);
    unsigned short* PQ  = (unsigned short*)(ws + CHB);
    unsigned short* PK  = PQ  + (size_t)CB * 4096;
    unsigned short* PVt = PK  + (size_t)CB * 8192;
    unsigned short* PO  = PVt + (size_t)CB * 8192;

    const int t = threadIdx.x;
    const int lane = t & 63, w = t >> 6, l15 = lane & 15, lhi = lane >> 4;
    const size_t rowbase = (size_t)b0 * 16 + (size_t)mt * 128;

    f32x4 acc[8];
    #pragma unroll
    for (int n = 0; n < 8; ++n) acc[n] = (f32x4){0.f, 0.f, 0.f, 0.f};

    for (int kh2 = 0; kh2 < 2; ++kh2) {
        // stage A half: 128 rows x 128 k, f32->bf16, XOR-swizzled
        #pragma unroll
        for (int it = 0; it < 8; ++it) {
            int idx = t + it * 512;
            int row = idx >> 5, c4 = idx & 31;
            float4 v = *(const float4*)(xsrc + (rowbase + row) * 256 + kh2 * 128 + c4 * 4);
            *(ushort4*)(As + row * 256 + (((unsigned)(c4 * 8)) ^ ((row & 7) << 4))) =
                pack4(v.x, v.y, v.z, v.w);
        }
        // stage B half: 32KB linear copy (bytes already pre-swizzled)
        #pragma unroll
        for (int it = 0; it < 4; ++it) {
            int u = t + it * 512;
            *(float4*)(Bs + u * 16) = *(const float4*)(wB + kh2 * 32768 + u * 16);
        }
        __syncthreads();
        for (int kt = 0; kt < 4; ++kt) {
            const int ks = kt * 64 + lhi * 16;
            bf16x8 af = *(const bf16x8*)(As + (w * 16 + l15) * 256 + (((unsigned)ks) ^ ((l15 & 7) << 4)));
            #pragma unroll
            for (int n = 0; n < 8; ++n) {
                bf16x8 bfr = *(const bf16x8*)(Bs + (n * 16 + l15) * 256 + (((unsigned)ks) ^ ((l15 & 7) << 4)));
                acc[n] = __builtin_amdgcn_mfma_f32_16x16x32_bf16(af, bfr, acc[n], 0, 0, 0);
            }
        }
        __syncthreads();
    }

    // epilogue
    #pragma unroll
    for (int n = 0; n < 8; ++n) {
        const int cit = n * 16 + l15;
        const float bias = biasall[cb_w * 128 + cit];
        #pragma unroll
        for (int r = 0; r < 4; ++r) {
            int rowl = mt * 128 + w * 16 + lhi * 4 + r;   // row within chunk
            int bi = rowl >> 4, qq = rowl & 15;
            unsigned short u = f2bf(acc[n][r] + bias);
            if (pid < 2)        PQ [(size_t)bi * 4096 + qq * 256 + pid * 128 + cit] = u;
            else if (pid < 4)   PK [(size_t)bi * 8192 + qq * 256 + (pid - 2) * 128 + cit] = u;
            else if (pid < 6)   PVt[(size_t)bi * 8192 + ((pid - 4) * 128 + cit) * 32 + qq] = u;
            else if (pid < 8)   PO [(size_t)bi * 4096 + qq * 256 + (pid - 6) * 128 + cit] = u;
            else if (pid < 10)  PK [(size_t)bi * 8192 + 4096 + qq * 256 + (pid - 8) * 128 + cit] = u;
            else                PVt[(size_t)bi * 8192 + ((pid - 10) * 128 + cit) * 32 + 16 + qq] = u;
        }
    }
}

// ---------------- K3: attention + sampling + out-proj (block=batch, wave=head) ----------------
__launch_bounds__(512, 4)
__global__ void mid_fused(const float* __restrict__ refpts, const float* __restrict__ query,
                          const float* __restrict__ bout, const unsigned char* __restrict__ ws,
                          float* __restrict__ out, int b0, int CB) {
    __shared__ __attribute__((aligned(16))) unsigned char wp_all[8192];  // 8 heads x [16q][32spos] bf16
    __shared__ __attribute__((aligned(16))) unsigned char accs[8192];    // [16q][256c] bf16 swz
    const int bi = blockIdx.x;
    const int gb = b0 + bi;
    const int t = threadIdx.x;
    const int lane = t & 63, h = t >> 6, l15 = lane & 15, lhi = lane >> 4;

    const unsigned short* PQ  = (const unsigned short*)(ws + CHB);
    const unsigned short* PK  = PQ  + (size_t)CB * 4096;
    const unsigned short* PVt = PK  + (size_t)CB * 8192;
    const unsigned short* PO  = PVt + (size_t)CB * 8192;
    const unsigned short* WoutT = (const unsigned short*)(ws + 524288);

    // ---- scores: S^T = kh @ qh^T  (lane: q=l15, k2 = lhi*4+r) ----
    bf16x8 qf = *(const bf16x8*)(PQ + (size_t)bi * 4096 + l15 * 256 + h * 32 + lhi * 8);
    bf16x8 k0 = *(const bf16x8*)(PK + (size_t)bi * 8192 + l15 * 256 + h * 32 + lhi * 8);
    bf16x8 k1 = *(const bf16x8*)(PK + (size_t)bi * 8192 + 4096 + l15 * 256 + h * 32 + lhi * 8);
    f32x4 z = (f32x4){0.f, 0.f, 0.f, 0.f};
    f32x4 S0 = __builtin_amdgcn_mfma_f32_16x16x32_bf16(k0, qf, z, 0, 0, 0);
    f32x4 S1 = __builtin_amdgcn_mfma_f32_16x16x32_bf16(k1, qf, z, 0, 0, 0);

    // ---- softmax over 16 keys (4 regs x 4 lhi-lanes), per seq ----
    float p0[4], p1[4];
    {
        float m = fmaxf(fmaxf(S0[0], S0[1]), fmaxf(S0[2], S0[3]));
        m = fmaxf(m, __shfl_xor(m, 16)); m = fmaxf(m, __shfl_xor(m, 32));
        float s = 0.f;
        #pragma unroll
        for (int r = 0; r < 4; ++r) { p0[r] = __expf(S0[r] - m); s += p0[r]; }
        s += __shfl_xor(s, 16); s += __shfl_xor(s, 32);
        float inv = 1.f / s;
        #pragma unroll
        for (int r = 0; r < 4; ++r) p0[r] *= inv;
    }
    {
        float m = fmaxf(fmaxf(S1[0], S1[1]), fmaxf(S1[2], S1[3]));
        m = fmaxf(m, __shfl_xor(m, 16)); m = fmaxf(m, __shfl_xor(m, 32));
        float s = 0.f;
        #pragma unroll
        for (int r = 0; r < 4; ++r) { p1[r] = __expf(S1[r] - m); s += p1[r]; }
        s += __shfl_xor(s, 16); s += __shfl_xor(s, 32);
        float inv = 1.f / s;
        #pragma unroll
        for (int r = 0; r < 4; ++r) p1[r] *= inv;
    }

    // ---- coords: lane = (q=l15, level=lhi); 4 points; pixel weights for its level ----
    float2 rp = *(const float2*)(refpts + (size_t)gb * 128 + l15 * 8 + lhi * 2);
    bf16x8 off8 = *(const bf16x8*)(PO + (size_t)bi * 4096 + l15 * 256 + h * 32 + lhi * 8);
    float w40[4] = {0.f, 0.f, 0.f, 0.f}, w41[4] = {0.f, 0.f, 0.f, 0.f};
    #pragma unroll
    for (int p = 0; p < 4; ++p) {
        float ox = (float)off8[2 * p], oy = (float)off8[2 * p + 1];
        float gx = 2.f * rp.x + ox - 0.5f;
        float gy = 2.f * rp.y + oy - 0.5f;
        float x0f = floorf(gx), y0f = floorf(gy);
        int ix0 = (int)x0f, iy0 = (int)y0f;
        float wx1 = gx - x0f, wx0 = 1.f - wx1;
        float wy1 = gy - y0f, wy0 = 1.f - wy1;
        #pragma unroll
        for (int c4 = 0; c4 < 4; ++c4) {
            int dy = c4 >> 1, dx = c4 & 1;
            int iy = iy0 + dy, ix = ix0 + dx;
            float cw = (dx ? wx1 : wx0) * (dy ? wy1 : wy0);
            bool valid = ((unsigned)ix < 2u) & ((unsigned)iy < 2u);
            cw = valid ? cw : 0.f;
            int pix = iy * 2 + ix;
            #pragma unroll
            for (int sl = 0; sl < 4; ++sl) {
                float add = (pix == sl) ? cw : 0.f;
                w40[sl] += add * p0[p];
                w41[sl] += add * p1[p];
            }
        }
    }
    unsigned char* wpb = wp_all + h * 1024;
    *(ushort4*)(wpb + l15 * 64 + lhi * 8)      = pack4(w40[0], w40[1], w40[2], w40[3]);
    *(ushort4*)(wpb + l15 * 64 + 32 + lhi * 8) = pack4(w41[0], w41[1], w41[2], w41[3]);
    __syncthreads();

    // ---- PV: out[q][d] = sum over K=32 (2 seqs x 16 positions), 0.5 mean factor ----
    bf16x8 aW = *(const bf16x8*)(wpb + l15 * 64 + lhi * 16);
    #pragma unroll
    for (int dh = 0; dh < 2; ++dh) {
        bf16x8 vf = *(const bf16x8*)(PVt + (size_t)bi * 8192 + (h * 32 + dh * 16 + l15) * 32 + lhi * 8);
        f32x4 c = __builtin_amdgcn_mfma_f32_16x16x32_bf16(aW, vf, z, 0, 0, 0);
        #pragma unroll
        for (int r = 0; r < 4; ++r) {
            int qq = lhi * 4 + r;
            int colg = h * 32 + dh * 16 + l15;
            *(unsigned short*)(accs + qq * 512 + (((unsigned)(colg * 2)) ^ ((qq & 7) << 4))) =
                f2bf(0.5f * c[r]);
        }
    }
    __syncthreads();

    // ---- out-proj: [16x256] @ WoutT, 2 col-tiles per wave ----
    f32x4 o2[2];
    o2[0] = z; o2[1] = z;
    for (int kt = 0; kt < 8; ++kt) {
        bf16x8 af = *(const bf16x8*)(accs + l15 * 512 + (((unsigned)(kt * 64 + lhi * 16)) ^ ((l15 & 7) << 4)));
        #pragma unroll
        for (int n2 = 0; n2 < 2; ++n2) {
            int coln = (h * 2 + n2) * 16 + l15;
            bf16x8 bfr = *(const bf16x8*)(WoutT + coln * 256 + kt * 32 + lhi * 8);
            o2[n2] = __builtin_amdgcn_mfma_f32_16x16x32_bf16(af, bfr, o2[n2], 0, 0, 0);
        }
    }
    #pragma unroll
    for (int n2 = 0; n2 < 2; ++n2) {
        int coln = (h * 2 + n2) * 16 + l15;
        float bo = bout[coln];
        #pragma unroll
        for (int r = 0; r < 4; ++r) {
            int qq = lhi * 4 + r;
            size_t idx = (size_t)gb * 4096 + qq * 256 + coln;
            out[idx] = o2[n2][r] + bo + query[idx];
        }
    }
}

extern "C" void kernel_launch(void* const* d_in, const int* in_sizes, int n_in,
                              void* d_out, int out_size, void* d_ws, size_t ws_size,
                              hipStream_t stream) {
    const float* query      = (const float*)d_in[0];
    const float* key_hist   = (const float*)d_in[1];
    const float* value_hist = (const float*)d_in[2];
    const float* refpts     = (const float*)d_in[3];
    const float* Wq   = (const float*)d_in[5];
    const float* bq   = (const float*)d_in[6];
    const float* Wk   = (const float*)d_in[7];
    const float* bk   = (const float*)d_in[8];
    const float* Wv   = (const float*)d_in[9];
    const float* bv   = (const float*)d_in[10];
    const float* Woff = (const float*)d_in[11];
    const float* boff = (const float*)d_in[12];
    const float* Wout = (const float*)d_in[13];
    const float* bout = (const float*)d_in[14];
    float* outp = (float*)d_out;
    unsigned char* ws = (unsigned char*)d_ws;

    const int bs = in_sizes[0] / (Q * E);          // 2048

    // chunk size: largest power-of-2 batch count whose buffers fit in ws
    int CB = bs;
    while (CB > 64 && (size_t)CHB + (size_t)CB * 49152u > ws_size) CB >>= 1;
    if (CB > bs) CB = bs;
    const int NCH = bs / CB;
    const int MT = CB / 8;

    wprep<<<1284, 256, 0, stream>>>(Wq, Wk, Wv, Woff, Wout, bq, bk, bv, boff, ws);
    for (int ch = 0; ch < NCH; ++ch) {
        const int b0 = ch * CB;
        proj_gemm<<<MT * 12, 512, 0, stream>>>(query, key_hist, value_hist, ws, b0, MT, CB);
        mid_fused<<<CB, 512, 0, stream>>>(refpts, query, bout, ws, outp, b0, CB);
    }
}

// Round 4
// 99.540 us; speedup vs baseline: 11.7729x; 1.5545x over previous
//
#include <hip/hip_runtime.h>

typedef float  f32x4  __attribute__((ext_vector_type(4)));
typedef __bf16 bf16x8 __attribute__((ext_vector_type(8)));

__device__ __forceinline__ unsigned short f2bf(float f) {
    union { float f; unsigned u; } v; v.f = f;
    unsigned r = v.u + 0x7FFFu + ((v.u >> 16) & 1u);
    return (unsigned short)(r >> 16);
}
__device__ __forceinline__ ushort4 pack4(float a, float b, float c, float d) {
    ushort4 o; o.x = f2bf(a); o.y = f2bf(b); o.z = f2bf(c); o.w = f2bf(d); return o;
}
union bfpack { unsigned short s[8]; bf16x8 v; };

// ws layout: [0, 512KB) proj frags WF[((h*4+mat)*2+nh)*8+kt][lane][8] bf16
//            [512KB, 640KB) out frags OF[nt*8+kt][lane][8] bf16
#define OF_OFF 524288

// ---- weight prep: fragment-major bf16 ----
__global__ void wprep(const float* __restrict__ Wq, const float* __restrict__ Wk,
                      const float* __restrict__ Wv, const float* __restrict__ Woff,
                      const float* __restrict__ Wout, unsigned short* __restrict__ ws) {
    int id = blockIdx.x * 256 + threadIdx.x;          // 0..327679
    if (id < 262144) {
        int tile = id >> 9, e = id & 511;
        int lane = e >> 3, j = e & 7;
        int kt = tile & 7, nh = (tile >> 3) & 1, mat = (tile >> 4) & 3, h = tile >> 6;
        int k = kt * 32 + (lane >> 4) * 8 + j;
        int col = h * 32 + nh * 16 + (lane & 15);
        const float* W = (mat == 0) ? Wq : (mat == 1) ? Wk : (mat == 2) ? Wv : Woff;
        ws[id] = f2bf(W[k * 256 + col]);
    } else {
        int i = id - 262144;                          // 0..65535
        int tile = i >> 9, e = i & 511;
        int lane = e >> 3, j = e & 7;
        int kt = tile & 7, nt = tile >> 3;
        int k = kt * 32 + (lane >> 4) * 8 + j;
        int col = nt * 16 + (lane & 15);
        ws[262144 + i] = f2bf(Wout[k * 256 + col]);
    }
}

// ---- fully-fused kernel: wave = batch, block = 8 batches ----
__launch_bounds__(512, 2)
__global__ void tsa_one(const float* __restrict__ query, const float* __restrict__ keyh,
                        const float* __restrict__ valh, const float* __restrict__ refpts,
                        const unsigned short* __restrict__ wsw,
                        const float* __restrict__ bq, const float* __restrict__ bk,
                        const float* __restrict__ bv, const float* __restrict__ boff,
                        const float* __restrict__ bout, float* __restrict__ out)
{
    // uni: staged B-frags [0,32KB) during GEMM phases; per-wave 6KB scratch between barriers
    __shared__ __attribute__((aligned(16))) unsigned char uni[49152];
    __shared__ __attribute__((aligned(16))) unsigned char accs[65536];  // 8 waves x 8KB swizzled
    const int t = threadIdx.x;
    const int lane = t & 63, w = t >> 6, l15 = lane & 15, lhi = lane >> 4;
    const long b = (long)blockIdx.x * 8 + w;

    // ---- A fragments: 3 sources x 16 rows x 256 k, direct global->reg, bf16 ----
    bf16x8 aq[8], ak[8], av[8];
    {
        const float* qp = query + b * 4096 + l15 * 256;
        const float* kp = keyh  + b * 4096 + l15 * 256;
        const float* vp = valh  + b * 4096 + l15 * 256;
        #pragma unroll
        for (int kt = 0; kt < 8; ++kt) {
            int o = kt * 32 + lhi * 8;
            float4 x0, x1; bfpack p;
            x0 = *(const float4*)(qp + o); x1 = *(const float4*)(qp + o + 4);
            p.s[0]=f2bf(x0.x); p.s[1]=f2bf(x0.y); p.s[2]=f2bf(x0.z); p.s[3]=f2bf(x0.w);
            p.s[4]=f2bf(x1.x); p.s[5]=f2bf(x1.y); p.s[6]=f2bf(x1.z); p.s[7]=f2bf(x1.w);
            aq[kt] = p.v;
            x0 = *(const float4*)(kp + o); x1 = *(const float4*)(kp + o + 4);
            p.s[0]=f2bf(x0.x); p.s[1]=f2bf(x0.y); p.s[2]=f2bf(x0.z); p.s[3]=f2bf(x0.w);
            p.s[4]=f2bf(x1.x); p.s[5]=f2bf(x1.y); p.s[6]=f2bf(x1.z); p.s[7]=f2bf(x1.w);
            ak[kt] = p.v;
            x0 = *(const float4*)(vp + o); x1 = *(const float4*)(vp + o + 4);
            p.s[0]=f2bf(x0.x); p.s[1]=f2bf(x0.y); p.s[2]=f2bf(x0.z); p.s[3]=f2bf(x0.w);
            p.s[4]=f2bf(x1.x); p.s[5]=f2bf(x1.y); p.s[6]=f2bf(x1.z); p.s[7]=f2bf(x1.w);
            av[kt] = p.v;
        }
    }
    // per-wave scratch: qh[0,1K) kh0[1K,2K) kh1[2K,3K) vT[3K,5K) off/Wp[5K,6K)
    unsigned char* scr = uni + w * 6144;
    const f32x4 z = (f32x4){0.f, 0.f, 0.f, 0.f};

    for (int h = 0; h < 8; ++h) {
        f32x4 acc[12];
        #pragma unroll
        for (int i = 0; i < 12; ++i) acc[i] = z;

        #pragma unroll 2
        for (int nh = 0; nh < 2; ++nh) {
            __syncthreads();   // prior Bbuf/scratch reads complete
            #pragma unroll
            for (int it = 0; it < 4; ++it) {
                int u = t + it * 512;
                int f = u >> 6;
                *(float4*)(uni + u * 16) =
                    *(const float4*)((const char*)wsw +
                        ((((h * 4 + (f >> 3)) * 2 + nh) * 8 + (f & 7)) << 10) + (u & 63) * 16);
            }
            __syncthreads();
            #pragma unroll
            for (int kt = 0; kt < 8; ++kt) {
                const unsigned char* bb = uni + kt * 1024 + lane * 16;
                bf16x8 b_q = *(const bf16x8*)(bb);
                bf16x8 b_k = *(const bf16x8*)(bb + 8192);
                bf16x8 b_v = *(const bf16x8*)(bb + 16384);
                bf16x8 b_o = *(const bf16x8*)(bb + 24576);
                acc[0 + nh]  = __builtin_amdgcn_mfma_f32_16x16x32_bf16(aq[kt], b_q, acc[0 + nh], 0, 0, 0);
                acc[2 + nh]  = __builtin_amdgcn_mfma_f32_16x16x32_bf16(aq[kt], b_k, acc[2 + nh], 0, 0, 0);
                acc[4 + nh]  = __builtin_amdgcn_mfma_f32_16x16x32_bf16(ak[kt], b_k, acc[4 + nh], 0, 0, 0);
                acc[6 + nh]  = __builtin_amdgcn_mfma_f32_16x16x32_bf16(aq[kt], b_v, acc[6 + nh], 0, 0, 0);
                acc[8 + nh]  = __builtin_amdgcn_mfma_f32_16x16x32_bf16(av[kt], b_v, acc[8 + nh], 0, 0, 0);
                acc[10 + nh] = __builtin_amdgcn_mfma_f32_16x16x32_bf16(aq[kt], b_o, acc[10 + nh], 0, 0, 0);
            }
        }
        __syncthreads();   // all waves done reading Bbuf; union becomes scratch

        // ---- epilogue scatter: bias + bf16 -> per-consumer layouts (wave-local) ----
        #pragma unroll 2
        for (int nh = 0; nh < 2; ++nh) {
            int dcol = nh * 16 + l15;
            int gcol = h * 32 + dcol;
            float bqv = bq[gcol], bkv = bk[gcol], bvv = bv[gcol], bov = boff[gcol];
            #pragma unroll
            for (int r = 0; r < 4; ++r) {
                int row = lhi * 4 + r;
                *(unsigned short*)(scr + row * 64 + dcol * 2)        = f2bf(acc[0 + nh][r] + bqv);
                *(unsigned short*)(scr + 1024 + row * 64 + dcol * 2) = f2bf(acc[2 + nh][r] + bkv);
                *(unsigned short*)(scr + 2048 + row * 64 + dcol * 2) = f2bf(acc[4 + nh][r] + bkv);
                *(unsigned short*)(scr + 3072 + dcol * 64 + row * 2)        = f2bf(acc[6 + nh][r] + bvv);
                *(unsigned short*)(scr + 3072 + dcol * 64 + 32 + row * 2)   = f2bf(acc[8 + nh][r] + bvv);
                *(unsigned short*)(scr + 5120 + row * 64 + dcol * 2) = f2bf(acc[10 + nh][r] + bov);
            }
        }

        // ---- scores: S^T = kh @ qh^T ----
        bf16x8 qf = *(const bf16x8*)(scr + l15 * 64 + lhi * 16);
        bf16x8 k0 = *(const bf16x8*)(scr + 1024 + l15 * 64 + lhi * 16);
        bf16x8 k1 = *(const bf16x8*)(scr + 2048 + l15 * 64 + lhi * 16);
        f32x4 S0 = __builtin_amdgcn_mfma_f32_16x16x32_bf16(k0, qf, z, 0, 0, 0);
        f32x4 S1 = __builtin_amdgcn_mfma_f32_16x16x32_bf16(k1, qf, z, 0, 0, 0);

        float p0[4], p1[4];
        {
            float m = fmaxf(fmaxf(S0[0], S0[1]), fmaxf(S0[2], S0[3]));
            m = fmaxf(m, __shfl_xor(m, 16)); m = fmaxf(m, __shfl_xor(m, 32));
            float s = 0.f;
            #pragma unroll
            for (int r = 0; r < 4; ++r) { p0[r] = __expf(S0[r] - m); s += p0[r]; }
            s += __shfl_xor(s, 16); s += __shfl_xor(s, 32);
            float inv = 1.f / s;
            #pragma unroll
            for (int r = 0; r < 4; ++r) p0[r] *= inv;
        }
        {
            float m = fmaxf(fmaxf(S1[0], S1[1]), fmaxf(S1[2], S1[3]));
            m = fmaxf(m, __shfl_xor(m, 16)); m = fmaxf(m, __shfl_xor(m, 32));
            float s = 0.f;
            #pragma unroll
            for (int r = 0; r < 4; ++r) { p1[r] = __expf(S1[r] - m); s += p1[r]; }
            s += __shfl_xor(s, 16); s += __shfl_xor(s, 32);
            float inv = 1.f / s;
            #pragma unroll
            for (int r = 0; r < 4; ++r) p1[r] *= inv;
        }

        // ---- coords: lane = (q=l15, level=lhi) -> per-pixel weights ----
        float2 rp = *(const float2*)(refpts + b * 128 + l15 * 8 + lhi * 2);
        bf16x8 off8 = *(const bf16x8*)(scr + 5120 + l15 * 64 + lhi * 16);
        float w40[4] = {0.f, 0.f, 0.f, 0.f}, w41[4] = {0.f, 0.f, 0.f, 0.f};
        #pragma unroll
        for (int p = 0; p < 4; ++p) {
            float ox = (float)off8[2 * p], oy = (float)off8[2 * p + 1];
            float gx = 2.f * rp.x + ox - 0.5f;
            float gy = 2.f * rp.y + oy - 0.5f;
            float x0f = floorf(gx), y0f = floorf(gy);
            int ix0 = (int)x0f, iy0 = (int)y0f;
            float wx1 = gx - x0f, wx0 = 1.f - wx1;
            float wy1 = gy - y0f, wy0 = 1.f - wy1;
            #pragma unroll
            for (int c4 = 0; c4 < 4; ++c4) {
                int dy = c4 >> 1, dx = c4 & 1;
                int iy = iy0 + dy, ix = ix0 + dx;
                float cw = (dx ? wx1 : wx0) * (dy ? wy1 : wy0);
                bool valid = ((unsigned)ix < 2u) & ((unsigned)iy < 2u);
                cw = valid ? cw : 0.f;
                int pix = iy * 2 + ix;
                #pragma unroll
                for (int sl = 0; sl < 4; ++sl) {
                    float add = (pix == sl) ? cw : 0.f;
                    w40[sl] += add * p0[p];
                    w41[sl] += add * p1[p];
                }
            }
        }
        *(ushort4*)(scr + 5120 + l15 * 64 + lhi * 8)      = pack4(w40[0], w40[1], w40[2], w40[3]);
        *(ushort4*)(scr + 5120 + l15 * 64 + 32 + lhi * 8) = pack4(w41[0], w41[1], w41[2], w41[3]);

        // ---- PV: K=32 over (2 seqs x 16 positions), 0.5 mean ----
        bf16x8 aW = *(const bf16x8*)(scr + 5120 + l15 * 64 + lhi * 16);
        #pragma unroll
        for (int dh = 0; dh < 2; ++dh) {
            bf16x8 vf = *(const bf16x8*)(scr + 3072 + (dh * 16 + l15) * 64 + lhi * 16);
            f32x4 c = __builtin_amdgcn_mfma_f32_16x16x32_bf16(aW, vf, z, 0, 0, 0);
            #pragma unroll
            for (int r = 0; r < 4; ++r) {
                int qq = lhi * 4 + r;
                int colg = h * 32 + dh * 16 + l15;
                *(unsigned short*)(accs + w * 8192 + qq * 512 + (((unsigned)(colg * 2)) ^ ((qq & 7) << 4))) =
                    f2bf(0.5f * c[r]);
            }
        }
    }

    // ---- out-projection: 4 quarters of 64 cols ----
    for (int qd = 0; qd < 4; ++qd) {
        __syncthreads();
        #pragma unroll
        for (int it = 0; it < 4; ++it) {
            int u = t + it * 512;
            *(float4*)(uni + u * 16) =
                *(const float4*)((const char*)wsw + OF_OFF + qd * 32768 + u * 16);
        }
        __syncthreads();
        f32x4 o4[4];
        #pragma unroll
        for (int i = 0; i < 4; ++i) o4[i] = z;
        #pragma unroll
        for (int kt = 0; kt < 8; ++kt) {
            bf16x8 afr = *(const bf16x8*)(accs + w * 8192 + l15 * 512 +
                                          (((unsigned)(kt * 64 + lhi * 16)) ^ ((l15 & 7) << 4)));
            #pragma unroll
            for (int ntl = 0; ntl < 4; ++ntl)
                o4[ntl] = __builtin_amdgcn_mfma_f32_16x16x32_bf16(
                    afr, *(const bf16x8*)(uni + (ntl * 8 + kt) * 1024 + lane * 16), o4[ntl], 0, 0, 0);
        }
        #pragma unroll
        for (int ntl = 0; ntl < 4; ++ntl) {
            int col = (qd * 4 + ntl) * 16 + l15;
            float bo = bout[col];
            #pragma unroll
            for (int r = 0; r < 4; ++r) {
                int qq = lhi * 4 + r;
                long idx = b * 4096 + qq * 256 + col;
                out[idx] = o4[ntl][r] + bo + query[idx];
            }
        }
    }
}

extern "C" void kernel_launch(void* const* d_in, const int* in_sizes, int n_in,
                              void* d_out, int out_size, void* d_ws, size_t ws_size,
                              hipStream_t stream) {
    const float* query      = (const float*)d_in[0];
    const float* key_hist   = (const float*)d_in[1];
    const float* value_hist = (const float*)d_in[2];
    const float* refpts     = (const float*)d_in[3];
    const float* Wq   = (const float*)d_in[5];
    const float* bq   = (const float*)d_in[6];
    const float* Wk   = (const float*)d_in[7];
    const float* bk   = (const float*)d_in[8];
    const float* Wv   = (const float*)d_in[9];
    const float* bv   = (const float*)d_in[10];
    const float* Woff = (const float*)d_in[11];
    const float* boff = (const float*)d_in[12];
    const float* Wout = (const float*)d_in[13];
    const float* bout = (const float*)d_in[14];
    float* outp = (float*)d_out;
    unsigned short* ws = (unsigned short*)d_ws;

    const int bs = in_sizes[0] / 4096;             // 2048
    wprep<<<1280, 256, 0, stream>>>(Wq, Wk, Wv, Woff, Wout, ws);
    tsa_one<<<bs / 8, 512, 0, stream>>>(query, key_hist, value_hist, refpts, ws,
                                        bq, bk, bv, boff, bout, outp);
}